// Round 1
// baseline (907.010 us; speedup 1.0000x reference)
//
#include <hip/hip_runtime.h>
#include <stdint.h>

typedef unsigned short u16;
typedef __bf16 bf16x8 __attribute__((ext_vector_type(8)));
typedef float f32x4 __attribute__((ext_vector_type(4)));
typedef unsigned short u16x8 __attribute__((ext_vector_type(8)));
typedef unsigned short u16x4 __attribute__((ext_vector_type(4)));

#define SK_EPS 1e-8f
#define S_T 20.60992915555662f   /* log2(e)/0.07 */
#define S_S 14.426950408889634f  /* log2(e)/0.1  */
#define INV_TT 14.285714285714286f
#define INV_TS 10.0f

__device__ __forceinline__ float b2f(u16 u){ return __uint_as_float(((unsigned)u)<<16); }
__device__ __forceinline__ u16 f2b(float f){
  unsigned u = __float_as_uint(f);
  u += 0x7FFFu + ((u>>16)&1u);   // RNE truncate to bf16 (finite data)
  return (u16)(u>>16);
}
__device__ __forceinline__ unsigned encf(float x){ unsigned u=__float_as_uint(x); return (u&0x80000000u)? ~u : (u|0x80000000u); }
__device__ __forceinline__ float decf(unsigned u){ return (u&0x80000000u)? __uint_as_float(u&0x7FFFFFFFu) : __uint_as_float(~u); }

__device__ __forceinline__ void gload16(const void* g, void* l){
  __builtin_amdgcn_global_load_lds((const __attribute__((address_space(1))) void*)g,
                                   (__attribute__((address_space(3))) void*)l, 16, 0, 0);
}

// ---------------- row normalize + bf16 cast ----------------
// block = 192 threads, one row of 768 f32 per block
__global__ __launch_bounds__(192) void norm_cast(const float* __restrict__ in, u16* __restrict__ out, int donorm){
  int row = blockIdx.x, tid = threadIdx.x;
  const float4* p = (const float4*)(in + (size_t)row*768);
  float4 v = p[tid];
  float ss = v.x*v.x + v.y*v.y + v.z*v.z + v.w*v.w;
  #pragma unroll
  for (int off=1; off<64; off<<=1) ss += __shfl_xor(ss, off);
  __shared__ float smem[3];
  int wv = tid>>6;
  if ((tid&63)==0) smem[wv] = ss;
  __syncthreads();
  float tot = smem[0]+smem[1]+smem[2];
  float scale = donorm ? (1.0f/fmaxf(sqrtf(tot), 1e-12f)) : 1.0f;
  u16x4 o;
  o[0]=f2b(v.x*scale); o[1]=f2b(v.y*scale); o[2]=f2b(v.z*scale); o[3]=f2b(v.w*scale);
  *(u16x4*)(out + (size_t)row*768 + tid*4) = o;
}

// ---------------- GEMM: C[M,N] = A[M,Kd] * B[N,Kd]^T (bf16 in, f32 acc) ----------------
// MODE 0: store bf16 C (t_logits)
// MODE 1: student epilogue -> sexp[m] += sum exp(s/Ts); sdot[m] += sum Q*s
// MODE 2: koleo epilogue -> maxd[m] = max off-diag dot (encoded uint)
template<int MODE>
__global__ __launch_bounds__(256) void gemm_bt(
    const u16* __restrict__ A, const u16* __restrict__ B, int Ndim, int Kd,
    u16* __restrict__ Cout,
    const u16* __restrict__ Tl, const float* __restrict__ a3, const float* __restrict__ b3,
    float* __restrict__ sexp, float* __restrict__ sdot, unsigned* __restrict__ maxd)
{
  __shared__ __align__(16) u16 As[128*64];
  __shared__ __align__(16) u16 Bs[128*64];
  int tid = threadIdx.x, lane = tid & 63, wave = tid >> 6;
  int wr = wave >> 1, wc = wave & 1;
  int nbn = Ndim >> 7;
  // XCD-aware swizzle (grid % 8 == 0 here)
  int nwg = gridDim.x, cpx = nwg >> 3;
  int bid = blockIdx.x;
  int swz = (bid & 7)*cpx + (bid >> 3);
  int tm = swz / nbn, tn = swz % nbn;
  int m0 = tm<<7, n0 = tn<<7;

  const f32x4 fzero = {0.f,0.f,0.f,0.f};
  f32x4 acc[4][4];
  #pragma unroll
  for (int i=0;i<4;++i)
    #pragma unroll
    for (int j=0;j<4;++j) acc[i][j] = fzero;

  int srcRow = lane>>3;                       // row within 8-row chunk
  int srcCol = (((lane&7) ^ (lane>>3)) << 3); // XOR-swizzled source column (elements)

  int nkt = Kd>>6;
  for (int kt=0; kt<nkt; ++kt){
    if (kt) __syncthreads();
    int k0 = kt<<6;
    #pragma unroll
    for (int c=0;c<4;++c){
      int chunk = (wave<<2)+c;
      int row = (chunk<<3) + srcRow;
      gload16(A + (size_t)(m0+row)*Kd + k0 + srcCol, (void*)(As + (chunk<<9)));
      gload16(B + (size_t)(n0+row)*Kd + k0 + srcCol, (void*)(Bs + (chunk<<9)));
    }
    asm volatile("s_waitcnt vmcnt(0)" ::: "memory");
    __syncthreads();
    #pragma unroll
    for (int ks=0; ks<2; ++ks){
      bf16x8 af[4], bfr[4];
      #pragma unroll
      for (int f=0; f<4; ++f){
        int rowA = (wr<<6)+(f<<4)+(lane&15);
        int idxA = ((rowA<<6) + (ks<<5) + ((lane>>4)<<3)) ^ ((lane&7)<<3);
        af[f] = *(const bf16x8*)(const void*)(As + idxA);
        int rowB = (wc<<6)+(f<<4)+(lane&15);
        int idxB = ((rowB<<6) + (ks<<5) + ((lane>>4)<<3)) ^ ((lane&7)<<3);
        bfr[f] = *(const bf16x8*)(const void*)(Bs + idxB);
      }
      #pragma unroll
      for (int fm=0;fm<4;++fm)
        #pragma unroll
        for (int fn=0;fn<4;++fn)
          acc[fm][fn] = __builtin_amdgcn_mfma_f32_16x16x32_bf16(af[fm], bfr[fn], acc[fm][fn], 0,0,0);
    }
  }

  if constexpr (MODE == 0){
    #pragma unroll
    for (int fm=0;fm<4;++fm)
      #pragma unroll
      for (int j=0;j<4;++j){
        size_t gr = (size_t)(m0 + (wr<<6)+(fm<<4)+((lane>>4)<<2)+j);
        #pragma unroll
        for (int fn=0;fn<4;++fn){
          int cl = (wc<<6)+(fn<<4)+(lane&15);
          Cout[gr*(size_t)Ndim + n0+cl] = f2b(acc[fm][fn][j]);
        }
      }
  } else if constexpr (MODE == 1){
    #pragma unroll
    for (int fm=0;fm<4;++fm)
      #pragma unroll
      for (int j=0;j<4;++j){
        size_t gr = (size_t)(m0 + (wr<<6)+(fm<<4)+((lane>>4)<<2)+j);
        float sx=0.f, sd=0.f;
        #pragma unroll
        for (int fn=0;fn<4;++fn){
          int cl = (wc<<6)+(fn<<4)+(lane&15);
          size_t gc = (size_t)(n0+cl);
          float v = acc[fm][fn][j];
          float tl = b2f(Tl[gr*(size_t)Ndim + gc]);
          sx += exp2f(v*S_S);
          sd += exp2f(tl*S_T)*a3[gc]*v;
        }
        #pragma unroll
        for (int off=1; off<16; off<<=1){ sx += __shfl_xor(sx,off); sd += __shfl_xor(sd,off); }
        if ((lane&15)==0){
          atomicAdd(&sexp[gr], sx);
          atomicAdd(&sdot[gr], b3[gr]*sd);
        }
      }
  } else {
    #pragma unroll
    for (int fm=0;fm<4;++fm)
      #pragma unroll
      for (int j=0;j<4;++j){
        size_t gr = (size_t)(m0 + (wr<<6)+(fm<<4)+((lane>>4)<<2)+j);
        float mx = -2.0f;
        #pragma unroll
        for (int fn=0;fn<4;++fn){
          int cl = (wc<<6)+(fn<<4)+(lane&15);
          size_t gc = (size_t)(n0+cl);
          float v = acc[fm][fn][j];
          if (gr != gc) mx = fmaxf(mx, v);
        }
        #pragma unroll
        for (int off=1; off<16; off<<=1) mx = fmaxf(mx, __shfl_xor(mx,off));
        if ((lane&15)==0) atomicMax(&maxd[gr], encf(mx));
      }
  }
}

// ---------------- Sinkhorn passes over t_logits (bf16 [M,K]) ----------------
// col sums: out[k] += sum_r exp(l[r][k]/Tt) * b[r]
__global__ __launch_bounds__(256) void sk_colsum(const u16* __restrict__ L, const float* __restrict__ bvec,
                                                 float* __restrict__ colOut, int Kc, int useb){
  int tid = threadIdx.x;
  int c0 = blockIdx.x*2048 + tid*8;
  int r0 = blockIdx.y*64;
  float acc[8] = {0.f,0.f,0.f,0.f,0.f,0.f,0.f,0.f};
  for (int r=r0; r<r0+64; ++r){
    u16x8 v = *(const u16x8*)(L + (size_t)r*Kc + c0);
    float bm = useb ? bvec[r] : 1.0f;
    #pragma unroll
    for (int i=0;i<8;++i) acc[i] += exp2f(b2f(v[i])*S_T)*bm;
  }
  #pragma unroll
  for (int i=0;i<8;++i) atomicAdd(&colOut[c0+i], acc[i]);
}

// row sums: rowR[m] = sum_k E*a[k]; mode&1: rowRE=sum E; mode&2: rowT=sum E*a*l
__global__ __launch_bounds__(256) void sk_rowsum(const u16* __restrict__ L, const float* __restrict__ avec,
    float* __restrict__ rowR, float* __restrict__ rowRE, float* __restrict__ rowT, int Kc, int mode){
  int m = blockIdx.x, tid = threadIdx.x;
  const u16* Lr = L + (size_t)m*Kc;
  float sR=0.f, sRE=0.f, sT=0.f;
  int nit = Kc/2048;
  for (int it=0; it<nit; ++it){
    int c = it*2048 + tid*8;
    u16x8 v = *(const u16x8*)(Lr + c);
    f32x4 alo = *(const f32x4*)(avec+c);
    f32x4 ahi = *(const f32x4*)(avec+c+4);
    #pragma unroll
    for (int i=0;i<8;++i){
      float l = b2f(v[i]);
      float E = exp2f(l*S_T);
      float a = (i<4)? alo[i] : ahi[i-4];
      float Ea = E*a;
      sR += Ea;
      if (mode&1) sRE += E;
      if (mode&2) sT += Ea*l;
    }
  }
  #pragma unroll
  for (int off=1; off<64; off<<=1){
    sR += __shfl_xor(sR,off);
    sRE += __shfl_xor(sRE,off);
    sT += __shfl_xor(sT,off);
  }
  __shared__ float red[3][4];
  int wv = tid>>6;
  if ((tid&63)==0){ red[0][wv]=sR; red[1][wv]=sRE; red[2][wv]=sT; }
  __syncthreads();
  if (tid==0){
    rowR[m] = red[0][0]+red[0][1]+red[0][2]+red[0][3];
    if (mode&1) rowRE[m] = red[1][0]+red[1][1]+red[1][2]+red[1][3];
    if (mode&2) rowT[m]  = red[2][0]+red[2][1]+red[2][2]+red[2][3];
  }
}

__global__ void upd_col(float* aV, float* colC, int K, int first){
  int k = blockIdx.x*256+threadIdx.x;
  if (k<K){
    float s = colC[k];
    float p = first ? 1.0f : aV[k];
    aV[k] = p/(p*s + SK_EPS);
    colC[k] = 0.0f;  // re-zero for next atomic pass
  }
}
__global__ void upd_row(float* bV, const float* rowR, int M, int first){
  int m = blockIdx.x*256+threadIdx.x;
  if (m<M){
    float R = rowR[m];
    float p = first ? 1.0f : bV[m];
    bV[m] = p/(p*R + SK_EPS);
  }
}
__global__ void fin_rows(float* bV, const float* rowR, const float* rowRE, const float* rowT,
                         float* sumQ, float* ttok, int M){
  int m = blockIdx.x*256+threadIdx.x;
  if (m<M){
    float p = bV[m], R = rowR[m];
    float b3 = p/(p*R + SK_EPS);
    bV[m] = b3;
    float sq = b3*R;           // exact row-sum of final Q
    sumQ[m] = sq;
    ttok[m] = logf(rowRE[m])*sq - b3*rowT[m]*INV_TT;
  }
}

// ---------------- final reduce ----------------
__global__ __launch_bounds__(1024) void finalize(const unsigned char* __restrict__ mask,
    const float* __restrict__ sexp, const float* __restrict__ sdot,
    const float* __restrict__ sumQ, const float* __restrict__ ttok,
    const unsigned* __restrict__ maxd, float* __restrict__ out, int M, int K){
  int tid = threadIdx.x;
  __shared__ int isBool;
  if (tid==0) isBool = 0;
  __syncthreads();
  int f = 0;
  for (int i=tid; i<M; i+=1024) if ((i&3) && mask[i]) f = 1;
  if (f) isBool = 1;
  __syncthreads();
  int ib = isBool;
  float cn=0.f, cc=0.f, ts=0.f, ks=0.f;
  for (int m=tid; m<M; m+=1024){
    int mk = ib ? (mask[m]!=0) : (((const int*)mask)[m]!=0);
    float pt = logf(sexp[m])*sumQ[m] - sdot[m]*INV_TS;
    if (mk){ cn += pt; cc += 1.0f; }
    ts += ttok[m];
  }
  for (int k=tid; k<K; k+=1024){
    float d = decf(maxd[k]);
    ks += logf(sqrtf(fmaxf(2.0f-2.0f*d, 0.0f)) + SK_EPS);
  }
  #pragma unroll
  for (int off=1; off<64; off<<=1){
    cn += __shfl_xor(cn,off); cc += __shfl_xor(cc,off);
    ts += __shfl_xor(ts,off); ks += __shfl_xor(ks,off);
  }
  __shared__ float red[4][16];
  int wv = tid>>6;
  if ((tid&63)==0){ red[0][wv]=cn; red[1][wv]=cc; red[2][wv]=ts; red[3][wv]=ks; }
  __syncthreads();
  if (tid==0){
    float CN=0,CC=0,TS=0,KS=0;
    for (int i=0;i<16;++i){ CN+=red[0][i]; CC+=red[1][i]; TS+=red[2][i]; KS+=red[3][i]; }
    out[0] = CN/fmaxf(CC,1.0f);
    out[1] = TS/(float)M;
    out[2] = -KS/(float)K;
  }
}

extern "C" void kernel_launch(void* const* d_in, const int* in_sizes, int n_in,
                              void* d_out, int out_size, void* d_ws, size_t ws_size,
                              hipStream_t stream){
  const float* teacher = (const float*)d_in[0];
  const float* student = (const float*)d_in[1];
  const unsigned char* mask = (const unsigned char*)d_in[2];
  const float* proto = (const float*)d_in[3];
  const int D = 768;
  const int M = in_sizes[0]/D;   // 8192
  const int K = in_sizes[3]/D;   // 8192
  float* out = (float*)d_out;

  char* ws = (char*)d_ws;
  size_t off = 0;
  auto alloc = [&](size_t bytes)->void*{ void* p = ws+off; off += (bytes+255)&~(size_t)255; return p; };
  u16* t_logits = (u16*)alloc((size_t)M*K*2);
  u16* t_hat    = (u16*)alloc((size_t)M*D*2);
  u16* s_hat    = (u16*)alloc((size_t)M*D*2);
  u16* w_bf     = (u16*)alloc((size_t)K*D*2);
  u16* w_hat    = (u16*)alloc((size_t)K*D*2);
  float* colC   = (float*)alloc((size_t)K*4);
  float* sexp   = (float*)alloc((size_t)M*4);
  float* sdot   = (float*)alloc((size_t)M*4);
  unsigned* maxd= (unsigned*)alloc((size_t)K*4);
  float* aV     = (float*)alloc((size_t)K*4);
  float* bV     = (float*)alloc((size_t)M*4);
  float* rowR   = (float*)alloc((size_t)M*4);
  float* rowRE  = (float*)alloc((size_t)M*4);
  float* rowT   = (float*)alloc((size_t)M*4);
  float* sumQ   = (float*)alloc((size_t)M*4);
  float* ttok   = (float*)alloc((size_t)M*4);

  hipMemsetAsync(colC, 0, (size_t)K*4, stream);
  hipMemsetAsync(sexp, 0, (size_t)M*4, stream);
  hipMemsetAsync(sdot, 0, (size_t)M*4, stream);
  hipMemsetAsync(maxd, 0, (size_t)K*4, stream);

  norm_cast<<<M, 192, 0, stream>>>(teacher, t_hat, 1);
  norm_cast<<<M, 192, 0, stream>>>(student, s_hat, 1);
  norm_cast<<<K, 192, 0, stream>>>(proto, w_bf, 0);
  norm_cast<<<K, 192, 0, stream>>>(proto, w_hat, 1);

  int nblk = (M/128)*(K/128);
  gemm_bt<0><<<nblk, 256, 0, stream>>>(t_hat, w_bf, K, D, t_logits,
                                       nullptr,nullptr,nullptr,nullptr,nullptr,nullptr);

  dim3 cgrid(K/2048, M/64);
  // SK iter 1
  sk_colsum<<<cgrid, 256, 0, stream>>>(t_logits, nullptr, colC, K, 0);
  upd_col<<<(K+255)/256, 256, 0, stream>>>(aV, colC, K, 1);
  sk_rowsum<<<M, 256, 0, stream>>>(t_logits, aV, rowR, rowRE, rowT, K, 1);
  upd_row<<<(M+255)/256, 256, 0, stream>>>(bV, rowR, M, 1);
  // SK iter 2
  sk_colsum<<<cgrid, 256, 0, stream>>>(t_logits, bV, colC, K, 1);
  upd_col<<<(K+255)/256, 256, 0, stream>>>(aV, colC, K, 0);
  sk_rowsum<<<M, 256, 0, stream>>>(t_logits, aV, rowR, rowRE, rowT, K, 0);
  upd_row<<<(M+255)/256, 256, 0, stream>>>(bV, rowR, M, 0);
  // SK iter 3
  sk_colsum<<<cgrid, 256, 0, stream>>>(t_logits, bV, colC, K, 1);
  upd_col<<<(K+255)/256, 256, 0, stream>>>(aV, colC, K, 0);
  sk_rowsum<<<M, 256, 0, stream>>>(t_logits, aV, rowR, rowRE, rowT, K, 2);
  fin_rows<<<(M+255)/256, 256, 0, stream>>>(bV, rowR, rowRE, rowT, sumQ, ttok, M);

  // student GEMM with fused CE epilogue (needs aV=a3, bV=b3)
  gemm_bt<1><<<nblk, 256, 0, stream>>>(s_hat, w_bf, K, D, nullptr,
                                       t_logits, aV, bV, sexp, sdot, nullptr);
  // koleo GEMM with fused row-max epilogue
  gemm_bt<2><<<nblk, 256, 0, stream>>>(w_hat, w_hat, K, D, nullptr,
                                       nullptr,nullptr,nullptr,nullptr,nullptr, maxd);

  finalize<<<1, 1024, 0, stream>>>(mask, sexp, sdot, sumQ, ttok, maxd, out, M, K);
}

// Round 2
// 755.364 us; speedup vs baseline: 1.2008x; 1.2008x over previous
//
#include <hip/hip_runtime.h>
#include <stdint.h>

typedef unsigned short u16;
typedef __bf16 bf16x8 __attribute__((ext_vector_type(8)));
typedef float f32x4 __attribute__((ext_vector_type(4)));
typedef unsigned short u16x8 __attribute__((ext_vector_type(8)));
typedef unsigned short u16x4 __attribute__((ext_vector_type(4)));

#define SK_EPS 1e-8f
#define S_T 20.60992915555662f   /* log2(e)/0.07 */
#define S_S 14.426950408889634f  /* log2(e)/0.1  */
#define INV_TT 14.285714285714286f
#define INV_TS 10.0f

__device__ __forceinline__ float b2f(u16 u){ return __uint_as_float(((unsigned)u)<<16); }
__device__ __forceinline__ u16 f2b(float f){
  unsigned u = __float_as_uint(f);
  u += 0x7FFFu + ((u>>16)&1u);   // RNE truncate to bf16 (finite data)
  return (u16)(u>>16);
}
__device__ __forceinline__ unsigned encf(float x){ unsigned u=__float_as_uint(x); return (u&0x80000000u)? ~u : (u|0x80000000u); }
__device__ __forceinline__ float decf(unsigned u){ return (u&0x80000000u)? __uint_as_float(u&0x7FFFFFFFu) : __uint_as_float(~u); }

__device__ __forceinline__ void gload16(const void* g, void* l){
  __builtin_amdgcn_global_load_lds((const __attribute__((address_space(1))) void*)g,
                                   (__attribute__((address_space(3))) void*)l, 16, 0, 0);
}

// ---------------- row normalize + bf16 cast ----------------
// block = 192 threads, one row of 768 f32 per block.
// out  = raw-cast (or normalized if out2==null&&donorm), out2 = normalized copy
__global__ __launch_bounds__(192) void norm_cast(const float* __restrict__ in, u16* __restrict__ out,
                                                 u16* __restrict__ out2, int donorm){
  int row = blockIdx.x, tid = threadIdx.x;
  const float4* p = (const float4*)(in + (size_t)row*768);
  float4 v = p[tid];
  float ss = v.x*v.x + v.y*v.y + v.z*v.z + v.w*v.w;
  #pragma unroll
  for (int off=1; off<64; off<<=1) ss += __shfl_xor(ss, off);
  __shared__ float smem[3];
  int wv = tid>>6;
  if ((tid&63)==0) smem[wv] = ss;
  __syncthreads();
  float tot = smem[0]+smem[1]+smem[2];
  float scale = donorm ? (1.0f/fmaxf(sqrtf(tot), 1e-12f)) : 1.0f;
  u16x4 o;
  o[0]=f2b(v.x); o[1]=f2b(v.y); o[2]=f2b(v.z); o[3]=f2b(v.w);
  u16x4 on;
  on[0]=f2b(v.x*scale); on[1]=f2b(v.y*scale); on[2]=f2b(v.z*scale); on[3]=f2b(v.w*scale);
  if (out2){
    *(u16x4*)(out  + (size_t)row*768 + tid*4) = o;   // raw
    *(u16x4*)(out2 + (size_t)row*768 + tid*4) = on;  // normalized
  } else {
    *(u16x4*)(out + (size_t)row*768 + tid*4) = donorm ? on : o;
  }
}

// ---------------- GEMM: C[M,N] = A[M,Kd]*B[N,Kd]^T, 256x256 tile, 512 thr ----
// MODE 0: store bf16 C + fused Sinkhorn col-sum (sum_r exp(l/Tt)) atomics
// MODE 1: student epilogue -> sexp[m] += sum exp(s/Ts); sdot[m] += b3*sum(Q~*s)
// MODE 2: koleo epilogue -> maxd[m] = max off-diag dot (encoded uint)
template<int MODE>
__global__ __launch_bounds__(512, 2) void gemm_bt(
    const u16* __restrict__ A, const u16* __restrict__ B, int Ndim, int Kd,
    u16* __restrict__ Cout, float* __restrict__ colC,
    const u16* __restrict__ Tl, const float* __restrict__ a3, const float* __restrict__ b3,
    float* __restrict__ sexp, float* __restrict__ sdot, unsigned* __restrict__ maxd)
{
  __shared__ __align__(16) u16 lds[65536];   // 128 KiB: 2 bufs x (A 32K + B 32K)
  int tid = threadIdx.x, lane = tid & 63, wave = tid >> 6;
  int wr = wave >> 2, wc = wave & 3;         // 2M x 4N wave grid, each wave 128x64 of C

  // XCD-aware supertile mapping: xcd owns 4 tile-rows; iterate 4-col stripes
  int bid = blockIdx.x, tm, tn;
  if (gridDim.x == 1024){
    int xcd = bid & 7, local = bid >> 3;     // local 0..127
    int g = local >> 4, w = local & 15;      // 8 col-groups x (4x4 supertile)
    tn = g*4 + (w & 3);
    tm = xcd*4 + (w >> 2);
  } else { int nbn = Ndim >> 8; tm = bid / nbn; tn = bid % nbn; }
  int m0 = tm << 8, n0 = tn << 8;

  const f32x4 fzero = {0.f,0.f,0.f,0.f};
  f32x4 acc[8][4];
  #pragma unroll
  for (int i=0;i<8;++i)
    #pragma unroll
    for (int j=0;j<4;++j) acc[i][j] = fzero;

  int srcRow = lane>>3;                        // row within 8-row chunk
  int srcCol = (((lane&7) ^ (lane>>3)) << 3);  // XOR-pre-swizzled source column

  const int nkt = Kd >> 6;                     // 12
  auto stage = [&](int p, int kt){
    int k0 = kt << 6;
    u16* As = lds + p*32768;
    u16* Bs = As + 16384;
    #pragma unroll
    for (int c=0;c<4;++c){
      int chunk = (wave<<2)+c;                 // 32 chunks of 8 rows x 64 cols
      int row = (chunk<<3) + srcRow;
      gload16(A + (size_t)(m0+row)*Kd + k0 + srcCol, (void*)(As + (chunk<<9)));
      gload16(B + (size_t)(n0+row)*Kd + k0 + srcCol, (void*)(Bs + (chunk<<9)));
    }
  };

  stage(0, 0);
  int p = 0;
  for (int kt=0; kt<nkt; ++kt){
    if (kt+1 < nkt){
      stage(p^1, kt+1);                        // prefetch next tile (8 loads)
      asm volatile("s_waitcnt vmcnt(8)" ::: "memory");  // only wait current tile
    } else {
      asm volatile("s_waitcnt vmcnt(0)" ::: "memory");
    }
    __builtin_amdgcn_s_barrier();
    __builtin_amdgcn_sched_barrier(0);
    const u16* As = lds + p*32768;
    const u16* Bs = As + 16384;
    #pragma unroll
    for (int ks=0; ks<2; ++ks){
      bf16x8 af[8], bfr[4];
      #pragma unroll
      for (int f=0; f<8; ++f){
        int rowA = (wr<<7)+(f<<4)+(lane&15);
        int idxA = ((rowA<<6) + (ks<<5) + ((lane>>4)<<3)) ^ ((lane&7)<<3);
        af[f] = *(const bf16x8*)(const void*)(As + idxA);
      }
      #pragma unroll
      for (int f=0; f<4; ++f){
        int rowB = (wc<<6)+(f<<4)+(lane&15);
        int idxB = ((rowB<<6) + (ks<<5) + ((lane>>4)<<3)) ^ ((lane&7)<<3);
        bfr[f] = *(const bf16x8*)(const void*)(Bs + idxB);
      }
      #pragma unroll
      for (int fm=0;fm<8;++fm)
        #pragma unroll
        for (int fn=0;fn<4;++fn)
          acc[fm][fn] = __builtin_amdgcn_mfma_f32_16x16x32_bf16(af[fm], bfr[fn], acc[fm][fn], 0,0,0);
    }
    __builtin_amdgcn_sched_barrier(0);
    __builtin_amdgcn_s_barrier();
    p ^= 1;
  }

  if constexpr (MODE == 0){
    float cs[4] = {0.f,0.f,0.f,0.f};
    #pragma unroll
    for (int fm=0;fm<8;++fm)
      #pragma unroll
      for (int j=0;j<4;++j){
        size_t gr = (size_t)(m0 + (wr<<7)+(fm<<4)+((lane>>4)<<2)+j);
        #pragma unroll
        for (int fn=0;fn<4;++fn){
          int cl = (wc<<6)+(fn<<4)+(lane&15);
          u16 hb = f2b(acc[fm][fn][j]);
          Cout[gr*(size_t)Ndim + n0+cl] = hb;
          cs[fn] += exp2f(b2f(hb)*S_T);
        }
      }
    #pragma unroll
    for (int fn=0;fn<4;++fn){
      float v = cs[fn];
      v += __shfl_xor(v,16); v += __shfl_xor(v,32);
      if (lane < 16) atomicAdd(&colC[n0 + (wc<<6)+(fn<<4)+lane], v);
    }
  } else if constexpr (MODE == 1){
    // stage this C-tile of t_logits into LDS (coalesced), then consume
    #pragma unroll
    for (int i=0;i<16;++i){
      int wch = (wave<<4) + i;                       // 128 chunks of 1 KiB
      int grow = (wch<<1) + (lane>>5);
      int gcol = (lane&31)<<3;
      gload16(Tl + (size_t)(m0+grow)*Ndim + n0 + gcol, (void*)(lds + (wch<<9)));
    }
    asm volatile("s_waitcnt vmcnt(0)" ::: "memory");
    __syncthreads();
    #pragma unroll
    for (int fm=0;fm<8;++fm)
      #pragma unroll
      for (int j=0;j<4;++j){
        int lrow = (wr<<7)+(fm<<4)+((lane>>4)<<2)+j;
        size_t gr = (size_t)(m0 + lrow);
        float sx=0.f, sd=0.f;
        #pragma unroll
        for (int fn=0;fn<4;++fn){
          int cl = (wc<<6)+(fn<<4)+(lane&15);
          size_t gc = (size_t)(n0+cl);
          float v = acc[fm][fn][j];
          float tl = b2f(lds[(size_t)lrow*256 + cl]);
          sx += exp2f(v*S_S);
          sd += exp2f(tl*S_T)*a3[gc]*v;
        }
        #pragma unroll
        for (int off=1; off<16; off<<=1){ sx += __shfl_xor(sx,off); sd += __shfl_xor(sd,off); }
        if ((lane&15)==0){
          atomicAdd(&sexp[gr], sx);
          atomicAdd(&sdot[gr], b3[gr]*sd);
        }
      }
  } else {
    #pragma unroll
    for (int fm=0;fm<8;++fm)
      #pragma unroll
      for (int j=0;j<4;++j){
        size_t gr = (size_t)(m0 + (wr<<7)+(fm<<4)+((lane>>4)<<2)+j);
        float mx = -2.0f;
        #pragma unroll
        for (int fn=0;fn<4;++fn){
          int cl = (wc<<6)+(fn<<4)+(lane&15);
          size_t gc = (size_t)(n0+cl);
          float v = acc[fm][fn][j];
          if (gr != gc) mx = fmaxf(mx, v);
        }
        #pragma unroll
        for (int off=1; off<16; off<<=1) mx = fmaxf(mx, __shfl_xor(mx,off));
        if ((lane&15)==0) atomicMax(&maxd[gr], encf(mx));
      }
  }
}

// ---------------- Sinkhorn passes over t_logits (bf16 [M,K]) ----------------
__global__ __launch_bounds__(256) void sk_colsum(const u16* __restrict__ L, const float* __restrict__ bvec,
                                                 float* __restrict__ colOut, int Kc, int useb){
  int tid = threadIdx.x;
  int c0 = blockIdx.x*2048 + tid*8;
  int r0 = blockIdx.y*64;
  float acc[8] = {0.f,0.f,0.f,0.f,0.f,0.f,0.f,0.f};
  for (int r=r0; r<r0+64; ++r){
    u16x8 v = *(const u16x8*)(L + (size_t)r*Kc + c0);
    float bm = useb ? bvec[r] : 1.0f;
    #pragma unroll
    for (int i=0;i<8;++i) acc[i] += exp2f(b2f(v[i])*S_T)*bm;
  }
  #pragma unroll
  for (int i=0;i<8;++i) atomicAdd(&colOut[c0+i], acc[i]);
}

__global__ __launch_bounds__(256) void sk_rowsum(const u16* __restrict__ L, const float* __restrict__ avec,
    float* __restrict__ rowR, float* __restrict__ rowRE, float* __restrict__ rowT, int Kc, int mode){
  int m = blockIdx.x, tid = threadIdx.x;
  const u16* Lr = L + (size_t)m*Kc;
  float sR=0.f, sRE=0.f, sT=0.f;
  int nit = Kc/2048;
  for (int it=0; it<nit; ++it){
    int c = it*2048 + tid*8;
    u16x8 v = *(const u16x8*)(Lr + c);
    f32x4 alo = *(const f32x4*)(avec+c);
    f32x4 ahi = *(const f32x4*)(avec+c+4);
    #pragma unroll
    for (int i=0;i<8;++i){
      float l = b2f(v[i]);
      float E = exp2f(l*S_T);
      float a = (i<4)? alo[i] : ahi[i-4];
      float Ea = E*a;
      sR += Ea;
      if (mode&1) sRE += E;
      if (mode&2) sT += Ea*l;
    }
  }
  #pragma unroll
  for (int off=1; off<64; off<<=1){
    sR += __shfl_xor(sR,off);
    sRE += __shfl_xor(sRE,off);
    sT += __shfl_xor(sT,off);
  }
  __shared__ float red[3][4];
  int wv = tid>>6;
  if ((tid&63)==0){ red[0][wv]=sR; red[1][wv]=sRE; red[2][wv]=sT; }
  __syncthreads();
  if (tid==0){
    rowR[m] = red[0][0]+red[0][1]+red[0][2]+red[0][3];
    if (mode&1) rowRE[m] = red[1][0]+red[1][1]+red[1][2]+red[1][3];
    if (mode&2) rowT[m]  = red[2][0]+red[2][1]+red[2][2]+red[2][3];
  }
}

__global__ void upd_col(float* aV, float* colC, int K, int first){
  int k = blockIdx.x*256+threadIdx.x;
  if (k<K){
    float s = colC[k];
    float p = first ? 1.0f : aV[k];
    aV[k] = p/(p*s + SK_EPS);
    colC[k] = 0.0f;  // re-zero for next atomic pass
  }
}
__global__ void upd_row(float* bV, const float* rowR, int M, int first){
  int m = blockIdx.x*256+threadIdx.x;
  if (m<M){
    float R = rowR[m];
    float p = first ? 1.0f : bV[m];
    bV[m] = p/(p*R + SK_EPS);
  }
}
__global__ void fin_rows(float* bV, const float* rowR, const float* rowRE, const float* rowT,
                         float* sumQ, float* ttok, int M){
  int m = blockIdx.x*256+threadIdx.x;
  if (m<M){
    float p = bV[m], R = rowR[m];
    float b3 = p/(p*R + SK_EPS);
    bV[m] = b3;
    float sq = b3*R;           // exact row-sum of final Q
    sumQ[m] = sq;
    ttok[m] = logf(rowRE[m])*sq - b3*rowT[m]*INV_TT;
  }
}

// ---------------- final reduce ----------------
__global__ __launch_bounds__(1024) void finalize(const unsigned char* __restrict__ mask,
    const float* __restrict__ sexp, const float* __restrict__ sdot,
    const float* __restrict__ sumQ, const float* __restrict__ ttok,
    const unsigned* __restrict__ maxd, float* __restrict__ out, int M, int K){
  int tid = threadIdx.x;
  __shared__ int isBool;
  if (tid==0) isBool = 0;
  __syncthreads();
  int f = 0;
  for (int i=tid; i<M; i+=1024) if ((i&3) && mask[i]) f = 1;
  if (f) isBool = 1;
  __syncthreads();
  int ib = isBool;
  float cn=0.f, cc=0.f, ts=0.f, ks=0.f;
  for (int m=tid; m<M; m+=1024){
    int mk = ib ? (mask[m]!=0) : (((const int*)mask)[m]!=0);
    float pt = logf(sexp[m])*sumQ[m] - sdot[m]*INV_TS;
    if (mk){ cn += pt; cc += 1.0f; }
    ts += ttok[m];
  }
  for (int k=tid; k<K; k+=1024){
    float d = decf(maxd[k]);
    ks += logf(sqrtf(fmaxf(2.0f-2.0f*d, 0.0f)) + SK_EPS);
  }
  #pragma unroll
  for (int off=1; off<64; off<<=1){
    cn += __shfl_xor(cn,off); cc += __shfl_xor(cc,off);
    ts += __shfl_xor(ts,off); ks += __shfl_xor(ks,off);
  }
  __shared__ float red[4][16];
  int wv = tid>>6;
  if ((tid&63)==0){ red[0][wv]=cn; red[1][wv]=cc; red[2][wv]=ts; red[3][wv]=ks; }
  __syncthreads();
  if (tid==0){
    float CN=0,CC=0,TS=0,KS=0;
    for (int i=0;i<16;++i){ CN+=red[0][i]; CC+=red[1][i]; TS+=red[2][i]; KS+=red[3][i]; }
    out[0] = CN/fmaxf(CC,1.0f);
    out[1] = TS/(float)M;
    out[2] = -KS/(float)K;
  }
}

extern "C" void kernel_launch(void* const* d_in, const int* in_sizes, int n_in,
                              void* d_out, int out_size, void* d_ws, size_t ws_size,
                              hipStream_t stream){
  const float* teacher = (const float*)d_in[0];
  const float* student = (const float*)d_in[1];
  const unsigned char* mask = (const unsigned char*)d_in[2];
  const float* proto = (const float*)d_in[3];
  const int D = 768;
  const int M = in_sizes[0]/D;   // 8192
  const int K = in_sizes[3]/D;   // 8192
  float* out = (float*)d_out;

  char* ws = (char*)d_ws;
  size_t off = 0;
  auto alloc = [&](size_t bytes)->void*{ void* p = ws+off; off += (bytes+255)&~(size_t)255; return p; };
  u16* t_logits = (u16*)alloc((size_t)M*K*2);
  u16* t_hat    = (u16*)alloc((size_t)M*D*2);
  u16* s_hat    = (u16*)alloc((size_t)M*D*2);
  u16* w_bf     = (u16*)alloc((size_t)K*D*2);
  u16* w_hat    = (u16*)alloc((size_t)K*D*2);
  float* colC   = (float*)alloc((size_t)K*4);
  float* sexp   = (float*)alloc((size_t)M*4);
  float* sdot   = (float*)alloc((size_t)M*4);
  unsigned* maxd= (unsigned*)alloc((size_t)K*4);
  float* aV     = (float*)alloc((size_t)K*4);
  float* bV     = (float*)alloc((size_t)M*4);
  float* rowR   = (float*)alloc((size_t)M*4);
  float* rowRE  = (float*)alloc((size_t)M*4);
  float* rowT   = (float*)alloc((size_t)M*4);
  float* sumQ   = (float*)alloc((size_t)M*4);
  float* ttok   = (float*)alloc((size_t)M*4);

  hipMemsetAsync(colC, 0, (size_t)K*4, stream);
  hipMemsetAsync(sexp, 0, (size_t)M*4, stream);
  hipMemsetAsync(sdot, 0, (size_t)M*4, stream);
  hipMemsetAsync(maxd, 0, (size_t)K*4, stream);

  norm_cast<<<M, 192, 0, stream>>>(teacher, t_hat, nullptr, 1);
  norm_cast<<<M, 192, 0, stream>>>(student, s_hat, nullptr, 1);
  norm_cast<<<K, 192, 0, stream>>>(proto, w_bf, w_hat, 1);  // raw + normalized in one pass

  int nblk = (M/256)*(K/256);    // 1024
  // GEMM0: t_logits + fused SK col-sum #1
  gemm_bt<0><<<nblk, 512, 0, stream>>>(t_hat, w_bf, K, D, t_logits, colC,
                                       nullptr,nullptr,nullptr,nullptr,nullptr,nullptr);

  dim3 cgrid(K/2048, M/64);
  // SK iter 1 (col-sum fused above)
  upd_col<<<(K+255)/256, 256, 0, stream>>>(aV, colC, K, 1);
  sk_rowsum<<<M, 256, 0, stream>>>(t_logits, aV, rowR, rowRE, rowT, K, 1);
  upd_row<<<(M+255)/256, 256, 0, stream>>>(bV, rowR, M, 1);
  // SK iter 2
  sk_colsum<<<cgrid, 256, 0, stream>>>(t_logits, bV, colC, K, 1);
  upd_col<<<(K+255)/256, 256, 0, stream>>>(aV, colC, K, 0);
  sk_rowsum<<<M, 256, 0, stream>>>(t_logits, aV, rowR, rowRE, rowT, K, 0);
  upd_row<<<(M+255)/256, 256, 0, stream>>>(bV, rowR, M, 0);
  // SK iter 3
  sk_colsum<<<cgrid, 256, 0, stream>>>(t_logits, bV, colC, K, 1);
  upd_col<<<(K+255)/256, 256, 0, stream>>>(aV, colC, K, 0);
  sk_rowsum<<<M, 256, 0, stream>>>(t_logits, aV, rowR, rowRE, rowT, K, 2);
  fin_rows<<<(M+255)/256, 256, 0, stream>>>(bV, rowR, rowRE, rowT, sumQ, ttok, M);

  // student GEMM with fused CE epilogue (aV=a3, bV=b3 final)
  gemm_bt<1><<<nblk, 512, 0, stream>>>(s_hat, w_bf, K, D, nullptr, nullptr,
                                       t_logits, aV, bV, sexp, sdot, nullptr);
  // koleo GEMM with fused row-max epilogue
  gemm_bt<2><<<nblk, 512, 0, stream>>>(w_hat, w_hat, K, D, nullptr, nullptr,
                                       nullptr,nullptr,nullptr,nullptr,nullptr, maxd);

  finalize<<<1, 1024, 0, stream>>>(mask, sexp, sdot, sumQ, ttok, maxd, out, M, K);
}